// Round 3
// 425.739 us; speedup vs baseline: 1.0050x; 1.0050x over previous
//
#include <hip/hip_runtime.h>

// InverseHaar: in (B=16, C=256, H=128, W=128) fp32 -> out (B=16, G=64, 2H=256, 2W=256) fp32
// c = quad*G + g ; a=quad0, h=quad1, v=quad2, d=quad3
// out[b,g,2y,2x]=tl  out[b,g,2y,2x+1]=tr  out[b,g,2y+1,2x]=bl  out[b,g,2y+1,2x+1]=br
//
// Mapping chosen for fully-packed wave stores: each thread handles 2 input
// x-positions (float2 per quad), so its per-row output is ONE float4 at
// column 4*x2. Across a 64-lane wave, each global_store_dwordx4 covers
// 1024 contiguous bytes (no 16B gaps — the float4-per-thread version
// half-filled every 64B granule per store instruction).

constexpr int B = 16, C = 256, H = 128, W = 128;
constexpr int G = C / 4;        // 64
constexpr int X2 = W / 2;       // 64 float2-chunks per input row == wave width
constexpr int PLANE = G * H * W;   // 1,048,576 elements between quads

__global__ __launch_bounds__(256) void inv_haar_kernel(const float* __restrict__ in,
                                                       float* __restrict__ out) {
    int tid = blockIdx.x * blockDim.x + threadIdx.x;
    // decompose tid -> (b, g, y, x2); all power-of-2 extents
    int x2 = tid & (X2 - 1);    // 0..63  -> input cols 2*x2, 2*x2+1
    int t  = tid >> 6;          // / 64
    int y  = t & (H - 1);
    t >>= 7;                    // / 128
    int g  = t & (G - 1);
    int b  = t >> 6;            // / 64

    int a_off = (((b * C + g) * H) + y) * W + (x2 << 1);
    const float2 av = *(const float2*)(in + a_off);
    const float2 hv = *(const float2*)(in + a_off + PLANE);
    const float2 vv = *(const float2*)(in + a_off + 2 * PLANE);
    const float2 dv = *(const float2*)(in + a_off + 3 * PLANE);

    float4 top, bot;
    {
        float s0 = av.x + hv.x, s1 = vv.x + dv.x;
        float d0 = av.x - hv.x, d1 = vv.x - dv.x;
        top.x = (s0 + s1) * 0.25f;   // tl
        top.y = (d0 + d1) * 0.25f;   // tr
        bot.x = (s0 - s1) * 0.25f;   // bl
        bot.y = (d0 - d1) * 0.25f;   // br
    }
    {
        float s0 = av.y + hv.y, s1 = vv.y + dv.y;
        float d0 = av.y - hv.y, d1 = vv.y - dv.y;
        top.z = (s0 + s1) * 0.25f;
        top.w = (d0 + d1) * 0.25f;
        bot.z = (s0 - s1) * 0.25f;
        bot.w = (d0 - d1) * 0.25f;
    }

    int o_top = (((b * G + g) * (2 * H)) + 2 * y) * (2 * W) + (x2 << 2);
    *(float4*)(out + o_top)         = top;   // row 2y   : 64 lanes x 16B contiguous
    *(float4*)(out + o_top + 2 * W) = bot;   // row 2y+1 : 64 lanes x 16B contiguous
}

extern "C" void kernel_launch(void* const* d_in, const int* in_sizes, int n_in,
                              void* d_out, int out_size, void* d_ws, size_t ws_size,
                              hipStream_t stream) {
    const float* in = (const float*)d_in[0];
    float* out = (float*)d_out;
    const int total_threads = B * G * H * X2;   // 8,388,608
    const int block = 256;
    const int grid = total_threads / block;     // 32,768
    inv_haar_kernel<<<grid, block, 0, stream>>>(in, out);
}